// Round 1
// baseline (48.956 us; speedup 1.0000x reference)
//
#include <hip/hip_runtime.h>

// Problem constants (match reference setup_inputs)
constexpr int B  = 16;
constexpr int T  = 32;
constexpr int NB = 8;
constexpr int L  = 128;
constexpr int V  = 50000;
constexpr int P  = NB * L;          // 1024 words per (b) source
constexpr int TOTAL = B * T * P;    // 524288 scatter elements
constexpr int OUT_ELEMS = B * T * V; // 25,600,000 floats

__global__ void zero_out_kernel(float4* __restrict__ out, int n4) {
    int i = blockIdx.x * blockDim.x + threadIdx.x;
    int stride = gridDim.x * blockDim.x;
    const float4 z = {0.f, 0.f, 0.f, 0.f};
    for (; i < n4; i += stride) out[i] = z;
}

__global__ void scatter_add_kernel(const float* __restrict__ bw,   // (B,T,NB)
                                   const float* __restrict__ att,  // (B,T,NB,L) == (B,T,P)
                                   const int*   __restrict__ idx,  // (B,NB,L) == (B,P)
                                   float*       __restrict__ out)  // (B,T,V)
{
    int tid = blockIdx.x * blockDim.x + threadIdx.x;
    if (tid >= TOTAL) return;
    int p  = tid & (P - 1);   // word within (nb,l)
    int bt = tid / P;         // b*T + t
    int b  = bt / T;

    float val = att[tid] * bw[bt * NB + (p >> 7)];  // p>>7 == p / L == nb
    int v = idx[b * P + p];
    atomicAdd(&out[bt * V + v], val);
}

extern "C" void kernel_launch(void* const* d_in, const int* in_sizes, int n_in,
                              void* d_out, int out_size, void* d_ws, size_t ws_size,
                              hipStream_t stream) {
    const float* bw  = (const float*)d_in[0];
    const float* att = (const float*)d_in[1];
    const int*   idx = (const int*)d_in[2];
    float* out = (float*)d_out;

    // 1) zero the output (dominant cost: 102.4 MB of writes)
    int n4 = OUT_ELEMS / 4;  // 25.6M divisible by 4
    zero_out_kernel<<<2048, 256, 0, stream>>>((float4*)out, n4);

    // 2) scatter-add
    int blocks = (TOTAL + 255) / 256;  // 2048
    scatter_add_kernel<<<blocks, 256, 0, stream>>>(bw, att, idx, out);
}

// Round 2
// 41.202 us; speedup vs baseline: 1.1882x; 1.1882x over previous
//
#include <hip/hip_runtime.h>

// Problem constants (match reference setup_inputs)
constexpr int B  = 16;
constexpr int T  = 32;
constexpr int NB = 8;
constexpr int L  = 128;
constexpr int V  = 50000;
constexpr int P  = NB * L;     // 1024 contributions per (b,t) row
constexpr int V4 = V / 4;      // 12500 float4 per row (V divisible by 4)

// One block per (b,t) output row. Phase 1: load this block's 1024
// contributions into registers. Phase 2: zero-fill the block's own row
// (float4 streaming stores). __syncthreads() drains vmcnt(0) before the
// barrier (gfx950 semantics), so the zeros are visible at L2 (the device
// coherence point for this block's XCD). Phase 3: atomicAdd the
// contributions into the row — all traffic to a row comes from exactly one
// block, so atomics only resolve intra-row duplicate indices (~10/1024),
// and the 200 KB row is still L2-hot from phase 2.
__global__ __launch_bounds__(256) void fused_scatter_kernel(
    const float* __restrict__ bw,   // (B,T,NB)
    const float* __restrict__ att,  // (B,T,NB,L) == (B,T,P)
    const int*   __restrict__ idx,  // (B,NB,L)   == (B,P)
    float*       __restrict__ out)  // (B,T,V)
{
    const int bt  = blockIdx.x;     // b*T + t, 0..511
    const int b   = bt >> 5;        // / T (T==32)
    const int tid = threadIdx.x;    // 0..255

    // Phase 1: 4 contributions per thread, coalesced loads.
    const float* attRow = att + bt * P;
    const float* bwRow  = bw  + bt * NB;
    const int*   idxRow = idx + b  * P;
    float val[4];
    int   v[4];
#pragma unroll
    for (int k = 0; k < 4; ++k) {
        const int p = tid + k * 256;
        val[k] = attRow[p] * bwRow[p >> 7];   // p>>7 == p/L == nb
        v[k]   = idxRow[p];
    }

    // Phase 2: zero this block's row. Row base is 16B-aligned
    // (bt*V*4 = bt*200000 bytes, divisible by 16).
    float*  row  = out + (size_t)bt * V;
    float4* row4 = reinterpret_cast<float4*>(row);
    const float4 z = make_float4(0.f, 0.f, 0.f, 0.f);
    for (int i = tid; i < V4; i += 256)
        row4[i] = z;

    __syncthreads();  // emits s_waitcnt vmcnt(0) + s_barrier: zeros visible

    // Phase 3: accumulate into own row (L2-hot).
#pragma unroll
    for (int k = 0; k < 4; ++k)
        atomicAdd(&row[v[k]], val[k]);
}

extern "C" void kernel_launch(void* const* d_in, const int* in_sizes, int n_in,
                              void* d_out, int out_size, void* d_ws, size_t ws_size,
                              hipStream_t stream) {
    const float* bw  = (const float*)d_in[0];
    const float* att = (const float*)d_in[1];
    const int*   idx = (const int*)d_in[2];
    float* out = (float*)d_out;

    fused_scatter_kernel<<<B * T, 256, 0, stream>>>(bw, att, idx, out);
}

// Round 3
// 22.208 us; speedup vs baseline: 2.2044x; 1.8553x over previous
//
#include <hip/hip_runtime.h>

// Problem constants (match reference setup_inputs)
constexpr int B  = 16;
constexpr int T  = 32;
constexpr int NB = 8;
constexpr int L  = 128;
constexpr int V  = 50000;
constexpr int P  = NB * L;            // 1024 contributions per (b,t) row

constexpr int NCHUNK = 4;             // vocab chunks per row
constexpr int CHUNK  = V / NCHUNK;    // 12500 floats = 50 KB LDS
constexpr int CHUNK4 = CHUNK / 4;     // 3125 float4 (50000 B % 16 == 0)

// One block per (row, vocab-chunk). Accumulate in LDS (ds_add_f32 atomics
// only resolve the ~1/50 intra-chunk duplicate indices), then stream the
// chunk to global as a pure write — no global atomics, no RMW fetch, and
// the streaming store is the final op so there is no vmcnt(0) drain stall.
// 50 KB LDS -> 3 blocks/CU = 12 waves/CU for store-latency hiding.
__global__ __launch_bounds__(256) void fused_lds_scatter_kernel(
    const float* __restrict__ bw,   // (B,T,NB)
    const float* __restrict__ att,  // (B,T,NB,L) == (B,T,P)
    const int*   __restrict__ idx,  // (B,NB,L)   == (B,P)
    float*       __restrict__ out)  // (B,T,V)
{
    __shared__ float buf[CHUNK];

    const int blk   = blockIdx.x;       // 0..2047; consecutive blocks write
    const int bt    = blk >> 2;         // contiguous chunks of the same row
    const int chunk = blk & (NCHUNK - 1);
    const int b     = bt >> 5;          // / T (T==32)
    const int tid   = threadIdx.x;      // 0..255
    const int lo    = chunk * CHUNK;

    // Zero LDS chunk (ds_write_b128).
    float4* buf4 = reinterpret_cast<float4*>(buf);
    const float4 z = make_float4(0.f, 0.f, 0.f, 0.f);
    for (int i = tid; i < CHUNK4; i += 256)
        buf4[i] = z;

    // Load this row's 1024 contributions (coalesced, overlaps LDS zeroing).
    const float* attRow = att + bt * P;
    const float* bwRow  = bw  + bt * NB;
    const int*   idxRow = idx + b  * P;
    float val[4];
    int   v[4];
#pragma unroll
    for (int k = 0; k < 4; ++k) {
        const int p = tid + k * 256;
        val[k] = attRow[p] * bwRow[p >> 7];   // p>>7 == p/L == nb
        v[k]   = idxRow[p] - lo;              // position within this chunk
    }

    __syncthreads();  // LDS zeros visible (lgkm drain only — cheap)

    // Scatter the ~CHUNK-range subset into LDS.
#pragma unroll
    for (int k = 0; k < 4; ++k)
        if ((unsigned)v[k] < (unsigned)CHUNK)
            atomicAdd(&buf[v[k]], val[k]);

    __syncthreads();

    // Stream chunk to global: pure float4 writes, last op in the kernel.
    // Offset bt*V + lo is 16B-aligned (200000*bt + 50000*chunk, both %16==0).
    float4* dst = reinterpret_cast<float4*>(out + (size_t)bt * V + lo);
    for (int i = tid; i < CHUNK4; i += 256)
        dst[i] = buf4[i];
}

extern "C" void kernel_launch(void* const* d_in, const int* in_sizes, int n_in,
                              void* d_out, int out_size, void* d_ws, size_t ws_size,
                              hipStream_t stream) {
    const float* bw  = (const float*)d_in[0];
    const float* att = (const float*)d_in[1];
    const int*   idx = (const int*)d_in[2];
    float* out = (float*)d_out;

    fused_lds_scatter_kernel<<<B * T * NCHUNK, 256, 0, stream>>>(bw, att, idx, out);
}

// Round 4
// 21.247 us; speedup vs baseline: 2.3041x; 1.0452x over previous
//
#include <hip/hip_runtime.h>

// Problem constants (match reference setup_inputs)
constexpr int B  = 16;
constexpr int T  = 32;
constexpr int NB = 8;
constexpr int L  = 128;
constexpr int V  = 50000;
constexpr int P  = NB * L;            // 1024 contributions per (b,t) row

constexpr int NCHUNK = 10;            // vocab chunks per row
constexpr int CHUNK  = V / NCHUNK;    // 5000 floats = 20000 B LDS
constexpr int CHUNK4 = CHUNK / 4;     // 1250 float4; chunk byte offset
                                      // (20000*chunk) is 16B-aligned

// One block per (row, vocab-chunk). Accumulate in LDS, then stream the
// chunk to global as a pure float4 write (last op -> no drain stall, no
// global atomics, no RMW fetch). 20000 B LDS -> 8 blocks/CU = 32 waves/CU
// (hardware max occupancy) for store-latency hiding; grid = 5120 = 20
// blocks/CU of work. Input rescan (x10 per row) stays L2-resident.
__global__ __launch_bounds__(256) void fused_lds_scatter_kernel(
    const float* __restrict__ bw,   // (B,T,NB)
    const float* __restrict__ att,  // (B,T,NB,L) == (B,T,P)
    const int*   __restrict__ idx,  // (B,NB,L)   == (B,P)
    float*       __restrict__ out)  // (B,T,V)
{
    __shared__ float buf[CHUNK];

    const int blk   = blockIdx.x;        // bt*NCHUNK + chunk
    const int bt    = blk / NCHUNK;      // consecutive blocks share a row,
    const int chunk = blk - bt * NCHUNK; // write contiguous vocab chunks
    const int b     = bt >> 5;           // / T (T==32)
    const int tid   = threadIdx.x;       // 0..255
    const int lo    = chunk * CHUNK;

    // Zero LDS chunk (ds_write_b128, conflict-free sequential pattern).
    float4* buf4 = reinterpret_cast<float4*>(buf);
    const float4 z = make_float4(0.f, 0.f, 0.f, 0.f);
    for (int i = tid; i < CHUNK4; i += 256)
        buf4[i] = z;

    // Load this row's 1024 contributions (coalesced; overlaps LDS zeroing).
    const float* attRow = att + bt * P;
    const float* bwRow  = bw  + bt * NB;
    const int*   idxRow = idx + b  * P;
    float val[4];
    int   v[4];
#pragma unroll
    for (int k = 0; k < 4; ++k) {
        const int p = tid + k * 256;
        val[k] = attRow[p] * bwRow[p >> 7];   // p>>7 == p/L == nb
        v[k]   = idxRow[p] - lo;              // position within this chunk
    }

    __syncthreads();  // LDS zeros visible (lgkm drain only — cheap)

    // Scatter the in-range subset (~1/10) into LDS.
#pragma unroll
    for (int k = 0; k < 4; ++k)
        if ((unsigned)v[k] < (unsigned)CHUNK)
            atomicAdd(&buf[v[k]], val[k]);

    __syncthreads();

    // Stream chunk to global: pure float4 writes, last op in the kernel.
    float4* dst = reinterpret_cast<float4*>(out + (size_t)bt * V + lo);
    for (int i = tid; i < CHUNK4; i += 256)
        dst[i] = buf4[i];
}

extern "C" void kernel_launch(void* const* d_in, const int* in_sizes, int n_in,
                              void* d_out, int out_size, void* d_ws, size_t ws_size,
                              hipStream_t stream) {
    const float* bw  = (const float*)d_in[0];
    const float* att = (const float*)d_in[1];
    const int*   idx = (const int*)d_in[2];
    float* out = (float*)d_out;

    fused_lds_scatter_kernel<<<B * T * NCHUNK, 256, 0, stream>>>(bw, att, idx, out);
}